// Round 8
// baseline (91.032 us; speedup 1.0000x reference)
//
#include <hip/hip_runtime.h>
#include <hip/hip_fp16.h>

namespace {
constexpr int kB = 2, kH = 16, kS = 2048, kD = 64, kBH = kB * kH;
constexpr int BQ = 128, BKV = 64;
constexpr int NQT = kS / BQ;   // 16
constexpr int NKT = kS / BKV;  // 32

typedef _Float16 f16x8 __attribute__((ext_vector_type(8)));
typedef _Float16 f16x4 __attribute__((ext_vector_type(4)));
typedef __fp16 fp16x2 __attribute__((ext_vector_type(2)));
typedef float f32x16 __attribute__((ext_vector_type(16)));
typedef float f32x4 __attribute__((ext_vector_type(4)));
typedef unsigned int u32;

// Q prescale: 1/sqrt(64) * log2(e) -> softmax done in exp2 domain.
constexpr float kQScale = 0.125f * 1.4426950408889634f;

// Packed LDS tile: 64 logical rows x 64 f16 -> 32 prows x 128 halfwords.
__device__ __forceinline__ int paddr(int row, int col) {
  const int prow = row >> 1;
  return prow * 128 + ((((row & 1) << 6) | col) ^ ((prow & 15) << 3));
}

__device__ __forceinline__ u32 pkrtz(float a, float b) {
  union { fp16x2 h; u32 u; } c;
  c.h = __builtin_amdgcn_cvt_pkrtz(a, b);
  return c.u;
}

// ---------------- preprocess: K fp32 -> f16 (same layout) ----------------
__global__ __launch_bounds__(256) void cvt_k_kernel(const float* __restrict__ K,
                                                    _Float16* __restrict__ Kh) {
  size_t i = ((size_t)blockIdx.x * 256 + threadIdx.x) * 8;
  float4 x = *(const float4*)(K + i);
  float4 y = *(const float4*)(K + i + 4);
  f16x8 o;
  o[0] = (_Float16)x.x; o[1] = (_Float16)x.y; o[2] = (_Float16)x.z; o[3] = (_Float16)x.w;
  o[4] = (_Float16)y.x; o[5] = (_Float16)y.y; o[6] = (_Float16)y.z; o[7] = (_Float16)y.w;
  *(f16x8*)(Kh + i) = o;
}

// ---------------- preprocess: V fp32 [bh][s][d] -> f16 V^T [bh][d][s] ----
__global__ __launch_bounds__(256) void tr_v_kernel(const float* __restrict__ V,
                                                   _Float16* __restrict__ Vt) {
  __shared__ _Float16 Vl[64 * 68];
  const int tid = threadIdx.x;
  const int bh = blockIdx.x >> 5;
  const int kt = blockIdx.x & 31;
  const float* vb = V + ((size_t)bh * kS + kt * 64) * kD;
#pragma unroll
  for (int i = 0; i < 4; ++i) {
    int off = (tid + 256 * i) * 4;
    int r = off >> 6, c = off & 63;
    float4 x = *(const float4*)(vb + (size_t)r * kD + c);
    Vl[(c + 0) * 68 + r] = (_Float16)x.x;
    Vl[(c + 1) * 68 + r] = (_Float16)x.y;
    Vl[(c + 2) * 68 + r] = (_Float16)x.z;
    Vl[(c + 3) * 68 + r] = (_Float16)x.w;
  }
  __syncthreads();
  const int d = tid >> 2, c0 = (tid & 3) * 16;
  _Float16* op = Vt + ((size_t)bh * kD + d) * kS + kt * 64 + c0;
#pragma unroll
  for (int j = 0; j < 4; ++j)
    *(f16x4*)(op + 4 * j) = *(const f16x4*)(Vl + d * 68 + c0 + 4 * j);
}

// ---------------- preprocess: mask int -> float bias 0 / -1e30 ----------
__global__ __launch_bounds__(256) void bias_kernel(const int* __restrict__ M,
                                                   float* __restrict__ Bias) {
  const int i = blockIdx.x * 256 + threadIdx.x;
  Bias[i] = M[i] ? 0.f : -1e30f;
}

// ------- main: wave-private KV LDS, zero barriers in the K-loop -------
// Each wave owns a 16KB LDS region (K 8KB + V 8KB, single-buffered) and
// free-runs; reg-prefetch (T14) of tile t+2 overlaps compute of tile t.
__global__ __launch_bounds__(256, 2) void fattn_wp(
    const _Float16* __restrict__ Kh, const _Float16* __restrict__ Vt,
    const float* __restrict__ Q, const float* __restrict__ Bias,
    float* __restrict__ O) {
  __shared__ __align__(16) char smem[65536];  // 4 waves x 16KB; Os overlay
  const int tid = threadIdx.x;
  const int lane = tid & 63;
  const int w = tid >> 6;    // wave 0..3
  const int q = lane & 31;   // qrow within wave tile
  const int h = lane >> 5;   // half 0/1

  // XCD-aware bijective swizzle (gridDim % 8 == 0).
  const int bid = blockIdx.x;
  const int cpx = gridDim.x >> 3;
  const int sbid = (bid & 7) * cpx + (bid >> 3);
  const int bh = sbid >> 4;
  const int qt = sbid & 15;
  const int q0 = qt * BQ;
  const int b = bh >> 4;  // H=16

  _Float16* Kw = (_Float16*)smem + w * 8192;  // wave-private K tile
  _Float16* Vw = Kw + 4096;                   // wave-private V tile
  float* Os = (float*)smem;                   // epilogue overlay [128][68]

  // Q fragments (B-operand), pre-scaled into exp2 domain.
  f16x8 qf[4];
  {
    const float* qp = Q + ((size_t)bh * kS + q0 + w * 32 + q) * kD;
#pragma unroll
    for (int dc = 0; dc < 4; ++dc) {
      const float* p = qp + dc * 16 + h * 8;
      float4 x = *(const float4*)p;
      float4 y = *(const float4*)(p + 4);
      f16x8 a;
      a[0] = (_Float16)(x.x * kQScale); a[1] = (_Float16)(x.y * kQScale);
      a[2] = (_Float16)(x.z * kQScale); a[3] = (_Float16)(x.w * kQScale);
      a[4] = (_Float16)(y.x * kQScale); a[5] = (_Float16)(y.y * kQScale);
      a[6] = (_Float16)(y.z * kQScale); a[7] = (_Float16)(y.w * kQScale);
      qf[dc] = a;
    }
  }

  f32x16 oa[2];
#pragma unroll
  for (int i = 0; i < 16; ++i) { oa[0][i] = 0.f; oa[1][i] = 0.f; }
  // m_run floor -30 (log2 units): exp2(bias - m_run) = 0 for masked keys.
  float m_run = -30.f, l_run = 0.f;

  const _Float16* kb = Kh + (size_t)bh * kS * kD;
  const _Float16* vb = Vt + (size_t)bh * kD * kS;
  const float* mbp = Bias + b * kS;

  // per-lane staging geometry: 8 granules of 8 f16 each for K and V
  const int row0 = lane >> 3;          // 0..7
  const int colg = (lane & 7) * 8;     // 0..56
  int ldso[8];
#pragma unroll
  for (int j = 0; j < 8; ++j) ldso[j] = paddr(row0 + 8 * j, colg);

  f16x8 kr[8], vr[8];
  auto load_tile = [&](int t0) {
    const _Float16* kp = kb + (size_t)t0 * kD + colg;
    const _Float16* vp = vb + t0 + colg;
#pragma unroll
    for (int j = 0; j < 8; ++j) {
      kr[j] = *(const f16x8*)(kp + (row0 + 8 * j) * kD);
      vr[j] = *(const f16x8*)(vp + (size_t)(row0 + 8 * j) * kS);
    }
  };
  auto write_tile = [&]() {
#pragma unroll
    for (int j = 0; j < 8; ++j) {
      *(f16x8*)(Kw + ldso[j]) = kr[j];
      *(f16x8*)(Vw + ldso[j]) = vr[j];
    }
  };

  // ---- QK^T (swapped), mask bias (global, L2-hot) as MFMA C-init ----
  auto qk = [&](int t0, f32x16 (&sd)[2]) {
    const float* mb = mbp + t0;
    __builtin_amdgcn_s_setprio(1);
#pragma unroll
    for (int mt = 0; mt < 2; ++mt) {
      f32x16 z;
#pragma unroll
      for (int g = 0; g < 4; ++g) {
        f32x4 mv = *(const f32x4*)(mb + mt * 32 + 8 * g + 4 * h);
        z[4 * g + 0] = mv[0]; z[4 * g + 1] = mv[1];
        z[4 * g + 2] = mv[2]; z[4 * g + 3] = mv[3];
      }
#pragma unroll
      for (int dc = 0; dc < 4; ++dc) {
        f16x8 kf = *(const f16x8*)(Kw + paddr(mt * 32 + q, dc * 16 + h * 8));
        z = __builtin_amdgcn_mfma_f32_32x32x16_f16(kf, qf[dc], z, 0, 0, 0);
      }
      sd[mt] = z;
    }
    __builtin_amdgcn_s_setprio(0);
  };

  // ---- prologue: stage tile 0; prefetch tile 1 into regs ----
  load_tile(0);
  write_tile();
  load_tile(BKV);

  f32x16 s[2];
  for (int t = 0; t < NKT; ++t) {
    qk(t * BKV, s);  // reads Kw (tile t; in-order DS guarantees data)

    // ---- softmax: tree max, defer-max (T13), exp2, tree sum ----
    float tm[16];
#pragma unroll
    for (int i = 0; i < 16; ++i) tm[i] = fmaxf(s[0][i], s[1][i]);
#pragma unroll
    for (int st = 8; st > 0; st >>= 1)
#pragma unroll
      for (int i = 0; i < st; ++i) tm[i] = fmaxf(tm[i], tm[i + st]);
    const float mx = fmaxf(tm[0], __shfl_xor(tm[0], 32));

    if (__any(mx > m_run + 8.f)) {
      const float mnew = fmaxf(m_run, mx);
      const float corr = __builtin_amdgcn_exp2f(m_run - mnew);
      m_run = mnew;
      l_run *= corr;
#pragma unroll
      for (int mt = 0; mt < 2; ++mt)
#pragma unroll
        for (int r = 0; r < 16; ++r) oa[mt][r] *= corr;
    }
    const float negm = -m_run;
#pragma unroll
    for (int mt = 0; mt < 2; ++mt)
#pragma unroll
      for (int r = 0; r < 16; ++r)
        s[mt][r] = __builtin_amdgcn_exp2f(s[mt][r] + negm);
    float tsum[16];
#pragma unroll
    for (int i = 0; i < 16; ++i) tsum[i] = s[0][i] + s[1][i];
#pragma unroll
    for (int st = 8; st > 0; st >>= 1)
#pragma unroll
      for (int i = 0; i < st; ++i) tsum[i] += tsum[i + st];
    l_run += tsum[0] + __shfl_xor(tsum[0], 32);

    // ---- pack P to f16 pairs ----
    u32 pkA[2][4], pkB[2][4];
#pragma unroll
    for (int mt = 0; mt < 2; ++mt)
#pragma unroll
      for (int g = 0; g < 4; ++g) {
        pkA[mt][g] = pkrtz(s[mt][4 * g + 0], s[mt][4 * g + 1]);
        pkB[mt][g] = pkrtz(s[mt][4 * g + 2], s[mt][4 * g + 3]);
      }

    // ---- PV (swapped): oa[md] += V^T * P ----
    __builtin_amdgcn_s_setprio(1);
#pragma unroll
    for (int kk = 0; kk < 4; ++kk) {
      const int e = kk & 1, mt = kk >> 1;
      u32 crossA = __shfl_xor(h ? pkA[mt][2 * e] : pkA[mt][2 * e + 1], 32);
      u32 crossB = __shfl_xor(h ? pkB[mt][2 * e] : pkB[mt][2 * e + 1], 32);
      union { u32 u[4]; f16x8 v; } pb;
      pb.u[0] = h ? crossA : pkA[mt][2 * e];
      pb.u[1] = h ? crossB : pkB[mt][2 * e];
      pb.u[2] = h ? pkA[mt][2 * e + 1] : crossA;
      pb.u[3] = h ? pkB[mt][2 * e + 1] : crossB;
#pragma unroll
      for (int md = 0; md < 2; ++md) {
        f16x8 vf = *(const f16x8*)(Vw + paddr(md * 32 + q, kk * 16 + h * 8));
        oa[md] = __builtin_amdgcn_mfma_f32_32x32x16_f16(vf, pb.v, oa[md], 0, 0, 0);
      }
    }
    __builtin_amdgcn_s_setprio(0);

    // ---- stage tile t+1 (regs -> LDS, after this tile's reads) ----
    if (t + 1 < NKT) {
      write_tile();
      if (t + 2 < NKT) load_tile((t + 2) * BKV);
    }
  }

  // ---- epilogue: normalize, transpose via LDS overlay, coalesced store ----
  __syncthreads();  // all waves done reading their Kw/Vw before Os overlay
  const float inv = 1.f / l_run;
#pragma unroll
  for (int mt = 0; mt < 2; ++mt)
#pragma unroll
    for (int r = 0; r < 16; ++r) {
      int d = mt * 32 + (r & 3) + 8 * (r >> 2) + 4 * h;
      Os[(w * 32 + q) * 68 + d] = oa[mt][r] * inv;
    }
  __syncthreads();
  {
    const int row = tid >> 1, cb = (tid & 1) * 32;
    float* op = O + ((size_t)bh * kS + q0 + row) * kD + cb;
    const float* sp = Os + row * 68 + cb;
#pragma unroll
    for (int j = 0; j < 8; ++j) *(float4*)(op + 4 * j) = *(const float4*)(sp + 4 * j);
  }
}

// ---------------- fallback (round-1 kernel) if ws is too small -------------
__device__ __forceinline__ int swz(int row, int colh) {
  return row * 64 + (colh ^ ((row & 7) << 3));
}

__global__ __launch_bounds__(256, 4) void fattn_fallback(
    const float* __restrict__ Q, const float* __restrict__ K,
    const float* __restrict__ V, const int* __restrict__ M,
    float* __restrict__ O) {
  __shared__ __align__(16) _Float16 Kl[64 * 64];
  __shared__ __align__(16) _Float16 Vtl[64 * 64];
  __shared__ __align__(16) _Float16 Pl[64 * 64];
  __shared__ float mbl[64];

  const int tid = threadIdx.x;
  const int lane = tid & 63;
  const int w = tid >> 6;
  const int lr = lane & 15;
  const int hg = lane >> 4;
  const int NQT1 = kS / 64;
  const int bh = blockIdx.x / NQT1;
  const int qt = blockIdx.x % NQT1;
  const int b = bh / kH;
  const int q0 = qt * 64;

  f16x8 aq[2];
  {
    const int row = q0 + w * 16 + lr;
    const float* qp = Q + ((size_t)bh * kS + row) * kD;
#pragma unroll
    for (int kf = 0; kf < 2; ++kf) {
      const float* p = qp + kf * 32 + hg * 8;
      float4 x = *(const float4*)(p);
      float4 y = *(const float4*)(p + 4);
      f16x8 a;
      a[0] = (_Float16)(x.x * 0.125f); a[1] = (_Float16)(x.y * 0.125f);
      a[2] = (_Float16)(x.z * 0.125f); a[3] = (_Float16)(x.w * 0.125f);
      a[4] = (_Float16)(y.x * 0.125f); a[5] = (_Float16)(y.y * 0.125f);
      a[6] = (_Float16)(y.z * 0.125f); a[7] = (_Float16)(y.w * 0.125f);
      aq[kf] = a;
    }
  }

  f32x4 oacc[4];
#pragma unroll
  for (int c = 0; c < 4; ++c) { oacc[c][0]=0.f; oacc[c][1]=0.f; oacc[c][2]=0.f; oacc[c][3]=0.f; }
  float m_run[4], l_run[4];
#pragma unroll
  for (int r = 0; r < 4; ++r) { m_run[r] = -1e30f; l_run[r] = 0.f; }

  const float* kb = K + (size_t)bh * kS * kD;
  const float* vb = V + (size_t)bh * kS * kD;
  const int* mbp = M + b * kS;

  for (int t0 = 0; t0 < kS; t0 += 64) {
    __syncthreads();
#pragma unroll
    for (int i = 0; i < 4; ++i) {
      const int off = (tid + 256 * i) * 4;
      const int row = off >> 6;
      const int col = off & 63;
      float4 kx = *(const float4*)(kb + (size_t)(t0 + row) * kD + col);
      f16x4 hk;
      hk[0] = (_Float16)kx.x; hk[1] = (_Float16)kx.y;
      hk[2] = (_Float16)kx.z; hk[3] = (_Float16)kx.w;
      *(f16x4*)(Kl + swz(row, col)) = hk;
      float4 vx = *(const float4*)(vb + (size_t)(t0 + row) * kD + col);
      Vtl[swz(col + 0, row)] = (_Float16)vx.x;
      Vtl[swz(col + 1, row)] = (_Float16)vx.y;
      Vtl[swz(col + 2, row)] = (_Float16)vx.z;
      Vtl[swz(col + 3, row)] = (_Float16)vx.w;
    }
    if (tid < 64) mbl[tid] = mbp[t0 + tid] ? 0.f : -1e30f;
    __syncthreads();

    f32x4 s[4];
#pragma unroll
    for (int c = 0; c < 4; ++c) {
      f32x4 z; z[0]=0.f; z[1]=0.f; z[2]=0.f; z[3]=0.f;
#pragma unroll
      for (int kf = 0; kf < 2; ++kf) {
        f16x8 bk = *(const f16x8*)(Kl + swz(c * 16 + lr, kf * 32 + hg * 8));
        z = __builtin_amdgcn_mfma_f32_16x16x32_f16(aq[kf], bk, z, 0, 0, 0);
      }
      const float mval = mbl[c * 16 + lr];
#pragma unroll
      for (int r = 0; r < 4; ++r) z[r] += mval;
      s[c] = z;
    }

    float tmax[4];
#pragma unroll
    for (int r = 0; r < 4; ++r)
      tmax[r] = fmaxf(fmaxf(s[0][r], s[1][r]), fmaxf(s[2][r], s[3][r]));
#pragma unroll
    for (int off = 1; off < 16; off <<= 1)
#pragma unroll
      for (int r = 0; r < 4; ++r) tmax[r] = fmaxf(tmax[r], __shfl_xor(tmax[r], off));

    float mnew[4], corr[4], tsum[4];
#pragma unroll
    for (int r = 0; r < 4; ++r) {
      mnew[r] = fmaxf(m_run[r], tmax[r]);
      corr[r] = __expf(m_run[r] - mnew[r]);
      m_run[r] = mnew[r];
      tsum[r] = 0.f;
    }
#pragma unroll
    for (int c = 0; c < 4; ++c)
#pragma unroll
      for (int r = 0; r < 4; ++r) {
        const float p = __expf(s[c][r] - mnew[r]);
        tsum[r] += p;
        Pl[swz(w * 16 + hg * 4 + r, c * 16 + lr)] = (_Float16)p;
      }
#pragma unroll
    for (int off = 1; off < 16; off <<= 1)
#pragma unroll
      for (int r = 0; r < 4; ++r) tsum[r] += __shfl_xor(tsum[r], off);
#pragma unroll
    for (int r = 0; r < 4; ++r) l_run[r] = l_run[r] * corr[r] + tsum[r];
#pragma unroll
    for (int c = 0; c < 4; ++c)
#pragma unroll
      for (int r = 0; r < 4; ++r) oacc[c][r] *= corr[r];

#pragma unroll
    for (int kf = 0; kf < 2; ++kf) {
      f16x8 pa = *(const f16x8*)(Pl + swz(w * 16 + lr, kf * 32 + hg * 8));
#pragma unroll
      for (int cd = 0; cd < 4; ++cd) {
        f16x8 vbf = *(const f16x8*)(Vtl + swz(cd * 16 + lr, kf * 32 + hg * 8));
        oacc[cd] = __builtin_amdgcn_mfma_f32_16x16x32_f16(pa, vbf, oacc[cd], 0, 0, 0);
      }
    }
  }

#pragma unroll
  for (int r = 0; r < 4; ++r) {
    const float inv = 1.f / l_run[r];
    const int row = q0 + w * 16 + hg * 4 + r;
    float* op = O + ((size_t)bh * kS + row) * kD;
#pragma unroll
    for (int cd = 0; cd < 4; ++cd) op[cd * 16 + lr] = oacc[cd][r] * inv;
  }
}
}  // namespace

extern "C" void kernel_launch(void* const* d_in, const int* in_sizes, int n_in,
                              void* d_out, int out_size, void* d_ws, size_t ws_size,
                              hipStream_t stream) {
  (void)in_sizes; (void)n_in; (void)out_size;
  const float* q = (const float*)d_in[0];
  const float* k = (const float*)d_in[1];
  const float* v = (const float*)d_in[2];
  const int* m = (const int*)d_in[3];
  float* o = (float*)d_out;

  const size_t elems = (size_t)kBH * kS * kD;           // 4.19M
  const size_t bias_elems = (size_t)kB * kS;            // 4096
  const size_t need = 2 * elems * sizeof(_Float16) + bias_elems * sizeof(float);

  if (ws_size >= need) {
    _Float16* Kh = (_Float16*)d_ws;
    _Float16* Vt = Kh + elems;
    float* Bias = (float*)(Vt + elems);
    hipLaunchKernelGGL(cvt_k_kernel, dim3(elems / 2048), dim3(256), 0, stream, k, Kh);
    hipLaunchKernelGGL(tr_v_kernel, dim3(kBH * (kS / 64)), dim3(256), 0, stream, v, Vt);
    hipLaunchKernelGGL(bias_kernel, dim3(bias_elems / 256), dim3(256), 0, stream, m, Bias);
    hipLaunchKernelGGL(fattn_wp, dim3(kBH * NQT), dim3(256), 0, stream,
                       Kh, Vt, q, Bias, o);
  } else {
    hipLaunchKernelGGL(fattn_fallback, dim3(kBH * (kS / 64)), dim3(256), 0, stream,
                       q, k, v, m, o);
  }
}

// Round 9
// 54.575 us; speedup vs baseline: 1.6680x; 1.6680x over previous
//
#include <hip/hip_runtime.h>
#include <hip/hip_fp16.h>

namespace {
constexpr int kB = 2, kH = 16, kS = 2048, kD = 64, kBH = kB * kH;
constexpr int BQ = 128, BKV = 64;
constexpr int NQT = kS / BQ;   // 16

typedef _Float16 f16x8 __attribute__((ext_vector_type(8)));
typedef _Float16 f16x4 __attribute__((ext_vector_type(4)));
typedef __fp16 fp16x2 __attribute__((ext_vector_type(2)));
typedef float f32x16 __attribute__((ext_vector_type(16)));
typedef float f32x4 __attribute__((ext_vector_type(4)));
typedef unsigned int u32;

// Q prescale: 1/sqrt(64) * log2(e) -> softmax done in exp2 domain.
constexpr float kQScale = 0.125f * 1.4426950408889634f;

// Packed LDS tile: 64 logical rows x 64 f16 -> 32 prows x 128 halfwords.
__device__ __forceinline__ int paddr(int row, int col) {
  const int prow = row >> 1;
  return prow * 128 + ((((row & 1) << 6) | col) ^ ((prow & 15) << 3));
}

__device__ __forceinline__ u32 pkrtz(float a, float b) {
  union { fp16x2 h; u32 u; } c;
  c.h = __builtin_amdgcn_cvt_pkrtz(a, b);
  return c.u;
}

// ---- preprocess 1: per-batch mask scan -> compaction index + bias + NT ----
__global__ __launch_bounds__(256) void scan_kernel(const int* __restrict__ M,
                                                   int* __restrict__ Idx,
                                                   float* __restrict__ BiasC,
                                                   int* __restrict__ NTarr) {
  const int b = blockIdx.x;
  const int tid = threadIdx.x;
  __shared__ int part[256];
  __shared__ int nvs;
  int m[8], sum = 0;
#pragma unroll
  for (int i = 0; i < 8; ++i) {
    m[i] = M[b * kS + tid * 8 + i];
    sum += m[i] ? 1 : 0;
  }
  part[tid] = sum;
  __syncthreads();
  for (int off = 1; off < 256; off <<= 1) {
    int v = (tid >= off) ? part[tid - off] : 0;
    __syncthreads();
    part[tid] += v;
    __syncthreads();
  }
  int run = part[tid] - sum;  // exclusive prefix
#pragma unroll
  for (int i = 0; i < 8; ++i)
    if (m[i]) Idx[b * kS + run++] = tid * 8 + i;
  if (tid == 255) nvs = part[255];
  __syncthreads();
  const int Nv = nvs;
  int NT = (Nv + 63) >> 6;
  if (NT == 0) NT = 1;
  const int pad = NT * 64;
  for (int j = Nv + tid; j < pad; j += 256) Idx[b * kS + j] = 0;
#pragma unroll
  for (int i = 0; i < 8; ++i) {
    const int j = tid * 8 + i;
    BiasC[b * kS + j] = (j < Nv) ? 0.f : -1e30f;
  }
  if (tid == 0) NTarr[b] = NT;
}

// ---- preprocess 2: gather+convert K fp32 -> compacted f16 [bh][j][d] ----
__global__ __launch_bounds__(256) void gather_k_kernel(
    const float* __restrict__ K, const int* __restrict__ Idx,
    const int* __restrict__ NTarr, _Float16* __restrict__ Kc) {
  const int e = blockIdx.x * 256 + threadIdx.x;  // [0, kBH*2048*8)
  const int bh = e >> 14;
  const int rem = e & 16383;
  const int j = rem >> 3;
  const int d0 = (rem & 7) << 3;
  const int b = bh >> 4;
  if (j >= NTarr[b] * 64) return;
  const int src = Idx[b * kS + j];
  const float* p = K + ((size_t)bh * kS + src) * kD + d0;
  float4 x = *(const float4*)p;
  float4 y = *(const float4*)(p + 4);
  f16x8 o;
  o[0] = (_Float16)x.x; o[1] = (_Float16)x.y; o[2] = (_Float16)x.z; o[3] = (_Float16)x.w;
  o[4] = (_Float16)y.x; o[5] = (_Float16)y.y; o[6] = (_Float16)y.z; o[7] = (_Float16)y.w;
  *(f16x8*)(Kc + ((size_t)bh * kS + j) * kD + d0) = o;
}

// ---- preprocess 3: gather V rows -> compacted transposed f16 [bh][d][j] ----
__global__ __launch_bounds__(256) void gather_vt_kernel(
    const float* __restrict__ V, const int* __restrict__ Idx,
    const int* __restrict__ NTarr, _Float16* __restrict__ Vtc) {
  __shared__ _Float16 Vl[64 * 68];
  __shared__ int ridx[64];
  const int tid = threadIdx.x;
  const int bh = blockIdx.x >> 5;
  const int jt = blockIdx.x & 31;
  const int b = bh >> 4;
  if (jt >= NTarr[b]) return;
  if (tid < 64) ridx[tid] = Idx[b * kS + jt * 64 + tid];
  __syncthreads();
  const float* vb = V + (size_t)bh * kS * kD;
#pragma unroll
  for (int i = 0; i < 4; ++i) {
    int off = (tid + 256 * i) * 4;
    int r = off >> 6, c = off & 63;
    float4 x = *(const float4*)(vb + (size_t)ridx[r] * kD + c);
    Vl[(c + 0) * 68 + r] = (_Float16)x.x;
    Vl[(c + 1) * 68 + r] = (_Float16)x.y;
    Vl[(c + 2) * 68 + r] = (_Float16)x.z;
    Vl[(c + 3) * 68 + r] = (_Float16)x.w;
  }
  __syncthreads();
  const int d = tid >> 2, c0 = (tid & 3) * 16;
  _Float16* op = Vtc + ((size_t)bh * kD + d) * kS + jt * 64 + c0;
#pragma unroll
  for (int j = 0; j < 4; ++j)
    *(f16x4*)(op + 4 * j) = *(const f16x4*)(Vl + d * 68 + c0 + 4 * j);
}

// ------- main: 32x32 swapped flash attention over COMPACTED keys -------
// R5 structure (best measured): shared double-buffered K/V staging,
// one barrier per tile, reg-prefetch (T14). Loop count NT[b] ~ 16.
__global__ __launch_bounds__(256, 2) void fattn_c(
    const _Float16* __restrict__ Kc, const _Float16* __restrict__ Vtc,
    const float* __restrict__ Q, const float* __restrict__ BiasC,
    const int* __restrict__ NTarr, float* __restrict__ O) {
  // K dbuf 16K | V dbuf 16K | bias dbuf 512B ; epilogue overlays the front.
  __shared__ __align__(16) char smem[16384 + 16384 + 512];
  _Float16* Kl = (_Float16*)smem;            // [2][32*128]
  _Float16* Vl = (_Float16*)(smem + 16384);  // [2][32*128]
  float* mbl = (float*)(smem + 32768);       // [2][64] bias 0 / -1e30
  float* Os = (float*)smem;                  // overlay [64][68]

  const int tid = threadIdx.x;
  const int lane = tid & 63;
  const int w = tid >> 6;    // wave 0..3
  const int q = lane & 31;   // qrow within wave tile
  const int h = lane >> 5;   // half 0/1

  // XCD-aware bijective swizzle (gridDim % 8 == 0).
  const int bid = blockIdx.x;
  const int cpx = gridDim.x >> 3;
  const int sbid = (bid & 7) * cpx + (bid >> 3);
  const int bh = sbid >> 4;
  const int qt = sbid & 15;
  const int q0 = qt * BQ;
  const int b = bh >> 4;  // H=16
  const int NT = NTarr[b];

  // Q fragments (B-operand), pre-scaled into exp2 domain.
  f16x8 qf[4];
  {
    const float* qp = Q + ((size_t)bh * kS + q0 + w * 32 + q) * kD;
#pragma unroll
    for (int dc = 0; dc < 4; ++dc) {
      const float* p = qp + dc * 16 + h * 8;
      float4 x = *(const float4*)p;
      float4 y = *(const float4*)(p + 4);
      f16x8 a;
      a[0] = (_Float16)(x.x * kQScale); a[1] = (_Float16)(x.y * kQScale);
      a[2] = (_Float16)(x.z * kQScale); a[3] = (_Float16)(x.w * kQScale);
      a[4] = (_Float16)(y.x * kQScale); a[5] = (_Float16)(y.y * kQScale);
      a[6] = (_Float16)(y.z * kQScale); a[7] = (_Float16)(y.w * kQScale);
      qf[dc] = a;
    }
  }

  f32x16 oa[2];
#pragma unroll
  for (int i = 0; i < 16; ++i) { oa[0][i] = 0.f; oa[1][i] = 0.f; }
  // m_run floor -30 (log2 units): exp2(bias - m_run) = 0 for pad keys.
  float m_run = -30.f, l_run = 0.f;

  const _Float16* kb = Kc + (size_t)bh * kS * kD;
  const _Float16* vb = Vtc + (size_t)bh * kD * kS;
  const float* mpc = BiasC + b * kS;

  // staging geometry: thread -> (row = tid>>2, colbase = (tid&3)*16)
  const int sr = tid >> 2, sc = (tid & 3) * 16;
  const int a0 = paddr(sr, sc), a1 = paddr(sr, sc + 8);

  // prologue stage tile 0 into buf 0
  {
    f16x8 k0 = *(const f16x8*)(kb + (size_t)sr * kD + sc);
    f16x8 k1 = *(const f16x8*)(kb + (size_t)sr * kD + sc + 8);
    f16x8 v0 = *(const f16x8*)(vb + (size_t)sr * kS + sc);
    f16x8 v1 = *(const f16x8*)(vb + (size_t)sr * kS + sc + 8);
    *(f16x8*)(Kl + a0) = k0; *(f16x8*)(Kl + a1) = k1;
    *(f16x8*)(Vl + a0) = v0; *(f16x8*)(Vl + a1) = v1;
    if (tid < 64) mbl[tid] = mpc[tid];
  }
  __syncthreads();

  int cur = 0;
  for (int t = 0; t < NT; ++t) {
    const int t0 = t * BKV;
    const bool pf = (t + 1 < NT);
    // ---- T14: issue next-tile global loads before compute ----
    f16x8 nk0, nk1, nv0, nv1;
    float nmv = 0.f;
    if (pf) {
      const int n0 = t0 + BKV;
      nk0 = *(const f16x8*)(kb + (size_t)(n0 + sr) * kD + sc);
      nk1 = *(const f16x8*)(kb + (size_t)(n0 + sr) * kD + sc + 8);
      nv0 = *(const f16x8*)(vb + (size_t)sr * kS + n0 + sc);
      nv1 = *(const f16x8*)(vb + (size_t)sr * kS + n0 + sc + 8);
      if (tid < 64) nmv = mpc[n0 + tid];
    }

    const _Float16* kd = Kl + cur * 4096;
    const _Float16* vd = Vl + cur * 4096;
    const float* mb = mbl + cur * 64;

    // ---- QK^T (swapped), bias folded in as the MFMA C-init ----
    // s[mt][4g+j] has key = mt*32 + 8g + 4h + j, qrow = q
    f32x16 s[2];
    __builtin_amdgcn_s_setprio(1);
#pragma unroll
    for (int mt = 0; mt < 2; ++mt) {
      f32x16 z;
#pragma unroll
      for (int g = 0; g < 4; ++g) {
        f32x4 mv = *(const f32x4*)(mb + mt * 32 + 8 * g + 4 * h);
        z[4 * g + 0] = mv[0]; z[4 * g + 1] = mv[1];
        z[4 * g + 2] = mv[2]; z[4 * g + 3] = mv[3];
      }
#pragma unroll
      for (int dc = 0; dc < 4; ++dc) {
        f16x8 kf = *(const f16x8*)(kd + paddr(mt * 32 + q, dc * 16 + h * 8));
        z = __builtin_amdgcn_mfma_f32_32x32x16_f16(kf, qf[dc], z, 0, 0, 0);
      }
      s[mt] = z;
    }
    __builtin_amdgcn_s_setprio(0);

    // ---- tile max + cross-half combine ----
    float mx = -3.0e38f;
#pragma unroll
    for (int mt = 0; mt < 2; ++mt)
#pragma unroll
      for (int r = 0; r < 16; r += 2)
        mx = fmaxf(fmaxf(mx, s[mt][r]), s[mt][r + 1]);
    mx = fmaxf(mx, __shfl_xor(mx, 32));

    // ---- defer-max (T13): only rescale when max grew by > 8 (log2) ----
    if (__any(mx > m_run + 8.f)) {
      const float mnew = fmaxf(m_run, mx);
      const float corr = __builtin_amdgcn_exp2f(m_run - mnew);
      m_run = mnew;
      l_run *= corr;
#pragma unroll
      for (int mt = 0; mt < 2; ++mt)
#pragma unroll
        for (int r = 0; r < 16; ++r) oa[mt][r] *= corr;
    }
    const float negm = -m_run;

    // ---- p = exp2(s - m); bounded by 2^8; pad keys -> 0 ----
    float ts = 0.f;
#pragma unroll
    for (int mt = 0; mt < 2; ++mt)
#pragma unroll
      for (int r = 0; r < 16; ++r) {
        float p = __builtin_amdgcn_exp2f(s[mt][r] + negm);
        s[mt][r] = p;
        ts += p;
      }
    ts += __shfl_xor(ts, 32);
    l_run += ts;

    // ---- pack P to f16 pairs ----
    u32 pkA[2][4], pkB[2][4];
#pragma unroll
    for (int mt = 0; mt < 2; ++mt)
#pragma unroll
      for (int g = 0; g < 4; ++g) {
        pkA[mt][g] = pkrtz(s[mt][4 * g + 0], s[mt][4 * g + 1]);
        pkB[mt][g] = pkrtz(s[mt][4 * g + 2], s[mt][4 * g + 3]);
      }

    // ---- PV (swapped): oa[md] += V^T * P ; B-frag built in-register ----
    __builtin_amdgcn_s_setprio(1);
#pragma unroll
    for (int kk = 0; kk < 4; ++kk) {
      const int e = kk & 1, mt = kk >> 1;
      u32 crossA = __shfl_xor(h ? pkA[mt][2 * e] : pkA[mt][2 * e + 1], 32);
      u32 crossB = __shfl_xor(h ? pkB[mt][2 * e] : pkB[mt][2 * e + 1], 32);
      union { u32 u[4]; f16x8 v; } pb;
      pb.u[0] = h ? crossA : pkA[mt][2 * e];
      pb.u[1] = h ? crossB : pkB[mt][2 * e];
      pb.u[2] = h ? pkA[mt][2 * e + 1] : crossA;
      pb.u[3] = h ? pkB[mt][2 * e + 1] : crossB;
#pragma unroll
      for (int md = 0; md < 2; ++md) {
        f16x8 vf = *(const f16x8*)(vd + paddr(md * 32 + q, kk * 16 + h * 8));
        oa[md] = __builtin_amdgcn_mfma_f32_32x32x16_f16(vf, pb.v, oa[md], 0, 0, 0);
      }
    }
    __builtin_amdgcn_s_setprio(0);

    // ---- write prefetched tile into the other buffer ----
    if (pf) {
      _Float16* kd2 = Kl + (cur ^ 1) * 4096;
      _Float16* vd2 = Vl + (cur ^ 1) * 4096;
      *(f16x8*)(kd2 + a0) = nk0; *(f16x8*)(kd2 + a1) = nk1;
      *(f16x8*)(vd2 + a0) = nv0; *(f16x8*)(vd2 + a1) = nv1;
      if (tid < 64) mbl[(cur ^ 1) * 64 + tid] = nmv;
    }
    __syncthreads();
    cur ^= 1;
  }

  // ---- epilogue: normalize, transpose via LDS, coalesced store ----
  const float inv = 1.f / l_run;
#pragma unroll
  for (int ph = 0; ph < 2; ++ph) {
    __syncthreads();
    if ((w >> 1) == ph) {
#pragma unroll
      for (int mt = 0; mt < 2; ++mt)
#pragma unroll
        for (int r = 0; r < 16; ++r) {
          int d = mt * 32 + (r & 3) + 8 * (r >> 2) + 4 * h;
          Os[((w & 1) * 32 + q) * 68 + d] = oa[mt][r] * inv;
        }
    }
    __syncthreads();
    {
      const int row = tid >> 2, cb = (tid & 3) * 16;
      float* op = O + ((size_t)bh * kS + q0 + ph * 64 + row) * kD + cb;
      const float* sp = Os + row * 68 + cb;
#pragma unroll
      for (int j = 0; j < 4; ++j) *(float4*)(op + 4 * j) = *(const float4*)(sp + 4 * j);
    }
  }
}

// ---------------- fallback (round-1 kernel) if ws is too small -------------
__device__ __forceinline__ int swz(int row, int colh) {
  return row * 64 + (colh ^ ((row & 7) << 3));
}

__global__ __launch_bounds__(256, 4) void fattn_fallback(
    const float* __restrict__ Q, const float* __restrict__ K,
    const float* __restrict__ V, const int* __restrict__ M,
    float* __restrict__ O) {
  __shared__ __align__(16) _Float16 Kl[64 * 64];
  __shared__ __align__(16) _Float16 Vtl[64 * 64];
  __shared__ __align__(16) _Float16 Pl[64 * 64];
  __shared__ float mbl[64];

  const int tid = threadIdx.x;
  const int lane = tid & 63;
  const int w = tid >> 6;
  const int lr = lane & 15;
  const int hg = lane >> 4;
  const int NQT1 = kS / 64;
  const int bh = blockIdx.x / NQT1;
  const int qt = blockIdx.x % NQT1;
  const int b = bh / kH;
  const int q0 = qt * 64;

  f16x8 aq[2];
  {
    const int row = q0 + w * 16 + lr;
    const float* qp = Q + ((size_t)bh * kS + row) * kD;
#pragma unroll
    for (int kf = 0; kf < 2; ++kf) {
      const float* p = qp + kf * 32 + hg * 8;
      float4 x = *(const float4*)(p);
      float4 y = *(const float4*)(p + 4);
      f16x8 a;
      a[0] = (_Float16)(x.x * 0.125f); a[1] = (_Float16)(x.y * 0.125f);
      a[2] = (_Float16)(x.z * 0.125f); a[3] = (_Float16)(x.w * 0.125f);
      a[4] = (_Float16)(y.x * 0.125f); a[5] = (_Float16)(y.y * 0.125f);
      a[6] = (_Float16)(y.z * 0.125f); a[7] = (_Float16)(y.w * 0.125f);
      aq[kf] = a;
    }
  }

  f32x4 oacc[4];
#pragma unroll
  for (int c = 0; c < 4; ++c) { oacc[c][0]=0.f; oacc[c][1]=0.f; oacc[c][2]=0.f; oacc[c][3]=0.f; }
  float m_run[4], l_run[4];
#pragma unroll
  for (int r = 0; r < 4; ++r) { m_run[r] = -1e30f; l_run[r] = 0.f; }

  const float* kb = K + (size_t)bh * kS * kD;
  const float* vb = V + (size_t)bh * kS * kD;
  const int* mbp = M + b * kS;

  for (int t0 = 0; t0 < kS; t0 += 64) {
    __syncthreads();
#pragma unroll
    for (int i = 0; i < 4; ++i) {
      const int off = (tid + 256 * i) * 4;
      const int row = off >> 6;
      const int col = off & 63;
      float4 kx = *(const float4*)(kb + (size_t)(t0 + row) * kD + col);
      f16x4 hk;
      hk[0] = (_Float16)kx.x; hk[1] = (_Float16)kx.y;
      hk[2] = (_Float16)kx.z; hk[3] = (_Float16)kx.w;
      *(f16x4*)(Kl + swz(row, col)) = hk;
      float4 vx = *(const float4*)(vb + (size_t)(t0 + row) * kD + col);
      Vtl[swz(col + 0, row)] = (_Float16)vx.x;
      Vtl[swz(col + 1, row)] = (_Float16)vx.y;
      Vtl[swz(col + 2, row)] = (_Float16)vx.z;
      Vtl[swz(col + 3, row)] = (_Float16)vx.w;
    }
    if (tid < 64) mbl[tid] = mbp[t0 + tid] ? 0.f : -1e30f;
    __syncthreads();

    f32x4 s[4];
#pragma unroll
    for (int c = 0; c < 4; ++c) {
      f32x4 z; z[0]=0.f; z[1]=0.f; z[2]=0.f; z[3]=0.f;
#pragma unroll
      for (int kf = 0; kf < 2; ++kf) {
        f16x8 bk = *(const f16x8*)(Kl + swz(c * 16 + lr, kf * 32 + hg * 8));
        z = __builtin_amdgcn_mfma_f32_16x16x32_f16(aq[kf], bk, z, 0, 0, 0);
      }
      const float mval = mbl[c * 16 + lr];
#pragma unroll
      for (int r = 0; r < 4; ++r) z[r] += mval;
      s[c] = z;
    }

    float tmax[4];
#pragma unroll
    for (int r = 0; r < 4; ++r)
      tmax[r] = fmaxf(fmaxf(s[0][r], s[1][r]), fmaxf(s[2][r], s[3][r]));
#pragma unroll
    for (int off = 1; off < 16; off <<= 1)
#pragma unroll
      for (int r = 0; r < 4; ++r) tmax[r] = fmaxf(tmax[r], __shfl_xor(tmax[r], off));

    float mnew[4], corr[4], tsum[4];
#pragma unroll
    for (int r = 0; r < 4; ++r) {
      mnew[r] = fmaxf(m_run[r], tmax[r]);
      corr[r] = __expf(m_run[r] - mnew[r]);
      m_run[r] = mnew[r];
      tsum[r] = 0.f;
    }
#pragma unroll
    for (int c = 0; c < 4; ++c)
#pragma unroll
      for (int r = 0; r < 4; ++r) {
        const float p = __expf(s[c][r] - mnew[r]);
        tsum[r] += p;
        Pl[swz(w * 16 + hg * 4 + r, c * 16 + lr)] = (_Float16)p;
      }
#pragma unroll
    for (int off = 1; off < 16; off <<= 1)
#pragma unroll
      for (int r = 0; r < 4; ++r) tsum[r] += __shfl_xor(tsum[r], off);
#pragma unroll
    for (int r = 0; r < 4; ++r) l_run[r] = l_run[r] * corr[r] + tsum[r];
#pragma unroll
    for (int c = 0; c < 4; ++c)
#pragma unroll
      for (int r = 0; r < 4; ++r) oacc[c][r] *= corr[r];

#pragma unroll
    for (int kf = 0; kf < 2; ++kf) {
      f16x8 pa = *(const f16x8*)(Pl + swz(w * 16 + lr, kf * 32 + hg * 8));
#pragma unroll
      for (int cd = 0; cd < 4; ++cd) {
        f16x8 vbf = *(const f16x8*)(Vtl + swz(cd * 16 + lr, kf * 32 + hg * 8));
        oacc[cd] = __builtin_amdgcn_mfma_f32_16x16x32_f16(pa, vbf, oacc[cd], 0, 0, 0);
      }
    }
  }

#pragma unroll
  for (int r = 0; r < 4; ++r) {
    const float inv = 1.f / l_run[r];
    const int row = q0 + w * 16 + hg * 4 + r;
    float* op = O + ((size_t)bh * kS + row) * kD;
#pragma unroll
    for (int cd = 0; cd < 4; ++cd) op[cd * 16 + lr] = oacc[cd][r] * inv;
  }
}
}  // namespace

extern "C" void kernel_launch(void* const* d_in, const int* in_sizes, int n_in,
                              void* d_out, int out_size, void* d_ws, size_t ws_size,
                              hipStream_t stream) {
  (void)in_sizes; (void)n_in; (void)out_size;
  const float* q = (const float*)d_in[0];
  const float* k = (const float*)d_in[1];
  const float* v = (const float*)d_in[2];
  const int* m = (const int*)d_in[3];
  float* o = (float*)d_out;

  const size_t elems = (size_t)kBH * kS * kD;  // 4.19M
  const size_t need = 2 * elems * sizeof(_Float16)        // Kc + Vtc
                    + (size_t)kB * kS * sizeof(int)       // Idx
                    + (size_t)kB * kS * sizeof(float)     // BiasC
                    + 256;                                // NTarr (padded)

  if (ws_size >= need) {
    _Float16* Kc = (_Float16*)d_ws;
    _Float16* Vtc = Kc + elems;
    int* Idx = (int*)(Vtc + elems);
    float* BiasC = (float*)(Idx + (size_t)kB * kS);
    int* NTarr = (int*)(BiasC + (size_t)kB * kS);
    hipLaunchKernelGGL(scan_kernel, dim3(kB), dim3(256), 0, stream, m, Idx, BiasC, NTarr);
    hipLaunchKernelGGL(gather_k_kernel, dim3((kBH * kS * 8) / 256), dim3(256), 0, stream,
                       k, Idx, NTarr, Kc);
    hipLaunchKernelGGL(gather_vt_kernel, dim3(kBH * (kS / 64)), dim3(256), 0, stream,
                       v, Idx, NTarr, Vtc);
    hipLaunchKernelGGL(fattn_c, dim3(kBH * NQT), dim3(256), 0, stream,
                       Kc, Vtc, q, BiasC, NTarr, o);
  } else {
    hipLaunchKernelGGL(fattn_fallback, dim3(kBH * (kS / 64)), dim3(256), 0, stream,
                       q, k, v, m, o);
  }
}